// Round 5
// baseline (10582.001 us; speedup 1.0000x reference)
//
#include <hip/hip_runtime.h>

// Problem constants (fixed by reference setup)
#define B_ 32
#define T_ 8192
#define I_ 16
#define H_ 128
#define P_ 1024
#define O_ 3

typedef _Float16 h2 __attribute__((ext_vector_type(2)));
typedef _Float16 h4 __attribute__((ext_vector_type(4)));
typedef _Float16 h8 __attribute__((ext_vector_type(8)));

// v_dot2_f32_f16: 2-way f16 dot, fp32 accumulate (CDNA dot insts)
#if __has_builtin(__builtin_amdgcn_fdot2)
#define FDOT2(a, b, c) __builtin_amdgcn_fdot2((a), (b), (c), false)
#else
__device__ __forceinline__ float fdot2_asm(h2 a, h2 b, float c) {
    asm("v_dot2_f32_f16 %0, %1, %2, %0" : "+v"(c) : "v"(a), "v"(b));
    return c;
}
#define FDOT2(a, b, c) fdot2_asm((a), (b), (c))
#endif

// ---- macro machinery: (gate g 0..3, m 0..3, e 0..3) ------------------------
#define FORME(M, g) M(g,0,0) M(g,0,1) M(g,0,2) M(g,0,3) \
                    M(g,1,0) M(g,1,1) M(g,1,2) M(g,1,3) \
                    M(g,2,0) M(g,2,1) M(g,2,2) M(g,2,3) \
                    M(g,3,0) M(g,3,1) M(g,3,2) M(g,3,3)
#define FORALL(M) FORME(M,0) FORME(M,1) FORME(M,2) FORME(M,3)
#define FORG(M) M(0) M(1) M(2) M(3)

// DPP (quad_perm / row_ror): pure-VALU cross-lane, no LDS round-trip.
#define DPPF(v, ctrl) \
    __int_as_float(__builtin_amdgcn_mov_dpp(__float_as_int(v), (ctrl), 0xF, 0xF, true))

// xor32-add via gfx950 v_permlane32_swap_b32 (pure VALU).
__device__ __forceinline__ float xor32_add(float p) {
    float a = p, b = p;
    asm("v_permlane32_swap_b32 %0, %1" : "+v"(a), "+v"(b));
    return a + b;
}

__device__ __forceinline__ float tanh_f(float x) {
    return 2.f / (1.f + __expf(-2.f * x)) - 1.f;
}
__device__ __forceinline__ h4 cvt4(float4 v) {
    return (h4){(_Float16)v.x, (_Float16)v.y, (_Float16)v.z, (_Float16)v.w};
}

// LDS-only barrier: drain DS ops + s_barrier, without __syncthreads' vmcnt(0)
// drain (x-prefetch loads are consumed via register dependency).
__device__ __forceinline__ void lds_barrier() {
    asm volatile("s_waitcnt lgkmcnt(0)\n\ts_barrier" ::: "memory");
}

// R10: TWO batches per THREAD (ILP form of the R9 idea; R9's wave-group
// split failed correctness for a cause not found by audit, so the 2x work
// is folded into each thread instead — same 4 waves, same single barrier,
// same indexing skeleton as the R7/R8 kernel that passed twice).
// Rationale: R6 (2 w/SIMD) == R7 (1 w/SIMD) == 733 ns/step and R8's
// clock-warm test was null => step is a ~1760-cy latency floor with ~half
// the issue slots idle. The second batch's fully-independent instruction
// stream fills those slots: ~2 batches per step interval. Weights are
// batch-independent -> the 80 weight VGPRs are SHARED; only accs/c/x/pend
// duplicate (~200 VGPRs, fits 512-cap at 1 wave/EU).
__global__ __launch_bounds__(256, 1) __attribute__((amdgpu_waves_per_eu(1, 1)))
void lstm_fused(
    const float* __restrict__ x,      // [B,T,16]
    const float* __restrict__ W_ih,   // [512,16]
    const float* __restrict__ W_hh,   // [512,128]
    const float* __restrict__ b_ih,   // [512]
    const float* __restrict__ b_hh,   // [512]
    const float* __restrict__ W_fc,   // [3,128]
    float* __restrict__ sums,         // [B,P,3]  (fully overwritten per block)
    float* __restrict__ counts)       // [B,P]    (fully overwritten per block)
{
    const int bx  = blockIdx.x;
    const int b0  = 2 * bx;
    const int b1  = 2 * bx + 1;
    const int tid = threadIdx.x;
    const int q   = tid >> 2;        // unit-pair index 0..63
    const int kc  = tid & 3;
    const int ja  = 2 * q;
    const int jb  = 2 * q + 1;

    __shared__ __align__(16) _Float16 hh[2][2][H_];       // [bat][buf][H]
    __shared__ __align__(16) _Float16 xt[2][2][16 * I_];  // [bat][buf][256]
    __shared__ float sums_lds[2][P_ * O_];                // 24 KB
    __shared__ float counts_lds[2][P_];                   // 8 KB

    // ---- weights -> f16 half2 named scalars (shared by both batches) ----
    const float* wrA0 = W_hh + (0 * H_ + ja) * H_;
    const float* wrA1 = W_hh + (1 * H_ + ja) * H_;
    const float* wrA2 = W_hh + (2 * H_ + ja) * H_;
    const float* wrA3 = W_hh + (3 * H_ + ja) * H_;
    const float* wrB0 = W_hh + (0 * H_ + jb) * H_;
    const float* wrB1 = W_hh + (1 * H_ + jb) * H_;
    const float* wrB2 = W_hh + (2 * H_ + jb) * H_;
    const float* wrB3 = W_hh + (3 * H_ + jb) * H_;
    // slot (g,m,e) holds W_hh[g*128+j][kc*8+32m+2e .. +1]
    #define WLOADA(g, m, e) h2 WA##g##_##m##_##e = (h2){ \
        (_Float16)wrA##g[kc * 8 + 32 * (m) + 2 * (e)], \
        (_Float16)wrA##g[kc * 8 + 32 * (m) + 2 * (e) + 1]};
    #define WLOADB(g, m, e) h2 WB##g##_##m##_##e = (h2){ \
        (_Float16)wrB##g[kc * 8 + 32 * (m) + 2 * (e)], \
        (_Float16)wrB##g[kc * 8 + 32 * (m) + 2 * (e) + 1]};
    FORALL(WLOADA)
    FORALL(WLOADB)

    // W_ih: gate g, x-chunk [kc*4, kc*4+4) as 2 half2, per unit
    #define ULOADA(g) \
        h2 UA##g##_0 = (h2){(_Float16)W_ih[((g) * H_ + ja) * I_ + kc * 4 + 0], \
                            (_Float16)W_ih[((g) * H_ + ja) * I_ + kc * 4 + 1]}; \
        h2 UA##g##_1 = (h2){(_Float16)W_ih[((g) * H_ + ja) * I_ + kc * 4 + 2], \
                            (_Float16)W_ih[((g) * H_ + ja) * I_ + kc * 4 + 3]};
    #define ULOADB(g) \
        h2 UB##g##_0 = (h2){(_Float16)W_ih[((g) * H_ + jb) * I_ + kc * 4 + 0], \
                            (_Float16)W_ih[((g) * H_ + jb) * I_ + kc * 4 + 1]}; \
        h2 UB##g##_1 = (h2){(_Float16)W_ih[((g) * H_ + jb) * I_ + kc * 4 + 2], \
                            (_Float16)W_ih[((g) * H_ + jb) * I_ + kc * 4 + 3]};
    FORG(ULOADA)
    FORG(ULOADB)

    // lane kc activates gate kc for both units (shared across batches)
    const float biasA = b_ih[kc * H_ + ja] + b_hh[kc * H_ + ja];
    const float biasB = b_ih[kc * H_ + jb] + b_hh[kc * H_ + jb];
    const float wfcA  = (kc < 3) ? W_fc[kc * H_ + ja] : 0.f;
    const float wfcB  = (kc < 3) ? W_fc[kc * H_ + jb] : 0.f;
    const bool  isg   = (kc == 2);

    // FC atomic lanes: reduce covers lane-xor {4,8,32}; xor16 handled by the
    // 2-way same-address atomic from lanes {kc, 16+kc} of each wave.
    const bool fc_lane = ((tid & 0x2C) == 0) && (kc < 3);

    // ---- init LDS ----
    for (int i = tid; i < P_ * O_; i += 256) {
        sums_lds[0][i] = 0.f; sums_lds[1][i] = 0.f;
    }
    for (int i = tid; i < P_; i += 256) {
        counts_lds[0][i] = 0.f; counts_lds[1][i] = 0.f;
    }
    if (tid < H_) {
        hh[0][0][tid] = (_Float16)0.f;
        hh[1][0][tid] = (_Float16)0.f;
    }

    const float* xb0 = x + (size_t)b0 * T_ * I_;
    const float* xb1 = x + (size_t)b1 * T_ * I_;
    float4 xr4_0 = make_float4(0.f, 0.f, 0.f, 0.f);
    float4 xr4_1 = make_float4(0.f, 0.f, 0.f, 0.f);
    if (tid < 64) {                       // tile 0 = steps 0..15, both batches
        xr4_0 = ((const float4*)xb0)[tid];
        xr4_1 = ((const float4*)xb1)[tid];
        *(h4*)&xt[0][0][tid * 4] = cvt4(xr4_0);
        *(h4*)&xt[1][0][tid * 4] = cvt4(xr4_1);
    }
    float cA_0 = 0.f, cB_0 = 0.f, cA_1 = 0.f, cB_1 = 0.f;
    float pend_p0 = 0.f, pend_p1 = 0.f;
    int   pend_id0 = 0, pend_id1 = 0;
    __syncthreads();

    #pragma unroll 1
    for (int t = 0; t < T_; ++t) {
        const int off = t & 15;
        const int btx = (t >> 4) & 1;
        const int bh  = t & 1;

        // ---- pipelined FC/count atomics from step t-1, both batches ----
        if (t != 0) {
            if (fc_lane) {
                if ((unsigned)pend_id0 < (unsigned)P_)
                    atomicAdd(&sums_lds[0][pend_id0 * O_ + kc], pend_p0);
                if ((unsigned)pend_id1 < (unsigned)P_)
                    atomicAdd(&sums_lds[1][pend_id1 * O_ + kc], pend_p1);
            }
            if (tid == 0) {
                if ((unsigned)pend_id0 < (unsigned)P_)
                    atomicAdd(&counts_lds[0][pend_id0], 1.f);
                if ((unsigned)pend_id1 < (unsigned)P_)
                    atomicAdd(&counts_lds[1][pend_id1], 1.f);
            }
        }

        // x prefetch (wave 0): issue tile t+16 at off==0, commit at off==8
        if (tid < 64) {
            if (off == 0 && t + 16 < T_) {
                xr4_0 = ((const float4*)(xb0 + (t + 16) * I_))[tid];
                xr4_1 = ((const float4*)(xb1 + (t + 16) * I_))[tid];
            }
            if (off == 8 && t + 8 < T_) {
                *(h4*)&xt[0][btx ^ 1][tid * 4] = cvt4(xr4_0);
                *(h4*)&xt[1][btx ^ 1][tid * 4] = cvt4(xr4_1);
            }
        }

        const h4 xv4_0 = *(const h4*)&xt[0][btx][off * I_ + kc * 4];
        const h4 xv4_1 = *(const h4*)&xt[1][btx][off * I_ + kc * 4];
        const h2 xv0_0 = __builtin_shufflevector(xv4_0, xv4_0, 0, 1);
        const h2 xv1_0 = __builtin_shufflevector(xv4_0, xv4_0, 2, 3);
        const h2 xv0_1 = __builtin_shufflevector(xv4_1, xv4_1, 0, 1);
        const h2 xv1_1 = __builtin_shufflevector(xv4_1, xv4_1, 2, 3);
        const int id0 = (int)(float)xt[0][btx][off * I_ + 2];  // exact (id<2048)
        const int id1 = (int)(float)xt[1][btx][off * I_ + 2];

        // 16 gate-row partials: (4 gates x 2 units) x 2 batches, kc h-slice.
        float aA0_0 = 0.f, aA1_0 = 0.f, aA2_0 = 0.f, aA3_0 = 0.f;
        float aB0_0 = 0.f, aB1_0 = 0.f, aB2_0 = 0.f, aB3_0 = 0.f;
        float aA0_1 = 0.f, aA1_1 = 0.f, aA2_1 = 0.f, aA3_1 = 0.f;
        float aB0_1 = 0.f, aB1_1 = 0.f, aB2_1 = 0.f, aB3_1 = 0.f;
        #define HDX(X, m) { \
            h8 hv = *(const h8*)&hh[X][bh][kc * 8 + 32 * (m)]; \
            h2 p0 = __builtin_shufflevector(hv, hv, 0, 1); \
            h2 p1 = __builtin_shufflevector(hv, hv, 2, 3); \
            h2 p2 = __builtin_shufflevector(hv, hv, 4, 5); \
            h2 p3 = __builtin_shufflevector(hv, hv, 6, 7); \
            aA0_##X = FDOT2(p0, WA0_##m##_0, aA0_##X); aA0_##X = FDOT2(p1, WA0_##m##_1, aA0_##X); \
            aA0_##X = FDOT2(p2, WA0_##m##_2, aA0_##X); aA0_##X = FDOT2(p3, WA0_##m##_3, aA0_##X); \
            aA1_##X = FDOT2(p0, WA1_##m##_0, aA1_##X); aA1_##X = FDOT2(p1, WA1_##m##_1, aA1_##X); \
            aA1_##X = FDOT2(p2, WA1_##m##_2, aA1_##X); aA1_##X = FDOT2(p3, WA1_##m##_3, aA1_##X); \
            aA2_##X = FDOT2(p0, WA2_##m##_0, aA2_##X); aA2_##X = FDOT2(p1, WA2_##m##_1, aA2_##X); \
            aA2_##X = FDOT2(p2, WA2_##m##_2, aA2_##X); aA2_##X = FDOT2(p3, WA2_##m##_3, aA2_##X); \
            aA3_##X = FDOT2(p0, WA3_##m##_0, aA3_##X); aA3_##X = FDOT2(p1, WA3_##m##_1, aA3_##X); \
            aA3_##X = FDOT2(p2, WA3_##m##_2, aA3_##X); aA3_##X = FDOT2(p3, WA3_##m##_3, aA3_##X); \
            aB0_##X = FDOT2(p0, WB0_##m##_0, aB0_##X); aB0_##X = FDOT2(p1, WB0_##m##_1, aB0_##X); \
            aB0_##X = FDOT2(p2, WB0_##m##_2, aB0_##X); aB0_##X = FDOT2(p3, WB0_##m##_3, aB0_##X); \
            aB1_##X = FDOT2(p0, WB1_##m##_0, aB1_##X); aB1_##X = FDOT2(p1, WB1_##m##_1, aB1_##X); \
            aB1_##X = FDOT2(p2, WB1_##m##_2, aB1_##X); aB1_##X = FDOT2(p3, WB1_##m##_3, aB1_##X); \
            aB2_##X = FDOT2(p0, WB2_##m##_0, aB2_##X); aB2_##X = FDOT2(p1, WB2_##m##_1, aB2_##X); \
            aB2_##X = FDOT2(p2, WB2_##m##_2, aB2_##X); aB2_##X = FDOT2(p3, WB2_##m##_3, aB2_##X); \
            aB3_##X = FDOT2(p0, WB3_##m##_0, aB3_##X); aB3_##X = FDOT2(p1, WB3_##m##_1, aB3_##X); \
            aB3_##X = FDOT2(p2, WB3_##m##_2, aB3_##X); aB3_##X = FDOT2(p3, WB3_##m##_3, aB3_##X); }
        HDX(0, 0) HDX(0, 1) HDX(0, 2) HDX(0, 3)
        HDX(1, 0) HDX(1, 1) HDX(1, 2) HDX(1, 3)
        // x contribution, both batches
        #define XC(X) \
            aA0_##X = FDOT2(xv0_##X, UA0_0, aA0_##X); aA0_##X = FDOT2(xv1_##X, UA0_1, aA0_##X); \
            aA1_##X = FDOT2(xv0_##X, UA1_0, aA1_##X); aA1_##X = FDOT2(xv1_##X, UA1_1, aA1_##X); \
            aA2_##X = FDOT2(xv0_##X, UA2_0, aA2_##X); aA2_##X = FDOT2(xv1_##X, UA2_1, aA2_##X); \
            aA3_##X = FDOT2(xv0_##X, UA3_0, aA3_##X); aA3_##X = FDOT2(xv1_##X, UA3_1, aA3_##X); \
            aB0_##X = FDOT2(xv0_##X, UB0_0, aB0_##X); aB0_##X = FDOT2(xv1_##X, UB0_1, aB0_##X); \
            aB1_##X = FDOT2(xv0_##X, UB1_0, aB1_##X); aB1_##X = FDOT2(xv1_##X, UB1_1, aB1_##X); \
            aB2_##X = FDOT2(xv0_##X, UB2_0, aB2_##X); aB2_##X = FDOT2(xv1_##X, UB2_1, aB2_##X); \
            aB3_##X = FDOT2(xv0_##X, UB3_0, aB3_##X); aB3_##X = FDOT2(xv1_##X, UB3_1, aB3_##X);
        XC(0)
        XC(1)

        // quad butterfly (xor1=0xB1, xor2=0x4E): all 4 lanes get all totals
        #define BFLY(ctrl, v) { float s_ = DPPF(v, ctrl); v += s_; }
        BFLY(0xB1, aA0_0) BFLY(0xB1, aA1_0) BFLY(0xB1, aA2_0) BFLY(0xB1, aA3_0)
        BFLY(0xB1, aB0_0) BFLY(0xB1, aB1_0) BFLY(0xB1, aB2_0) BFLY(0xB1, aB3_0)
        BFLY(0xB1, aA0_1) BFLY(0xB1, aA1_1) BFLY(0xB1, aA2_1) BFLY(0xB1, aA3_1)
        BFLY(0xB1, aB0_1) BFLY(0xB1, aB1_1) BFLY(0xB1, aB2_1) BFLY(0xB1, aB3_1)
        BFLY(0x4E, aA0_0) BFLY(0x4E, aA1_0) BFLY(0x4E, aA2_0) BFLY(0x4E, aA3_0)
        BFLY(0x4E, aB0_0) BFLY(0x4E, aB1_0) BFLY(0x4E, aB2_0) BFLY(0x4E, aB3_0)
        BFLY(0x4E, aA0_1) BFLY(0x4E, aA1_1) BFLY(0x4E, aA2_1) BFLY(0x4E, aA3_1)
        BFLY(0x4E, aB0_1) BFLY(0x4E, aB1_1) BFLY(0x4E, aB2_1) BFLY(0x4E, aB3_1)

        // activation + cell update + h, per batch (lane kc owns gate kc)
        #define ACT(X) \
            float hnA_##X, hnB_##X; { \
            float tgA = (kc == 0) ? aA0_##X : (kc == 1) ? aA1_##X : (kc == 2) ? aA2_##X : aA3_##X; \
            float tgB = (kc == 0) ? aB0_##X : (kc == 1) ? aB1_##X : (kc == 2) ? aB2_##X : aB3_##X; \
            tgA += biasA; tgB += biasB; \
            const float argA = isg ? (tgA + tgA) : tgA; \
            const float argB = isg ? (tgB + tgB) : tgB; \
            const float sfA  = 1.f / (1.f + __expf(-argA)); \
            const float sfB  = 1.f / (1.f + __expf(-argB)); \
            const float actA = isg ? (sfA + sfA - 1.f) : sfA; \
            const float actB = isg ? (sfB + sfB - 1.f) : sfB; \
            const float giA = DPPF(actA, 0x00); const float gfA = DPPF(actA, 0x55); \
            const float ggA = DPPF(actA, 0xAA); const float goA = DPPF(actA, 0xFF); \
            const float giB = DPPF(actB, 0x00); const float gfB = DPPF(actB, 0x55); \
            const float ggB = DPPF(actB, 0xAA); const float goB = DPPF(actB, 0xFF); \
            cA_##X = fmaf(gfA, cA_##X, giA * ggA); \
            cB_##X = fmaf(gfB, cB_##X, giB * ggB); \
            hnA_##X = goA * tanh_f(cA_##X); \
            hnB_##X = goB * tanh_f(cB_##X); }
        ACT(0)
        ACT(1)

        if (kc == 0) {      // publish h_t: contiguous f16 pair, one b32 write
            *(h2*)&hh[0][bh ^ 1][ja] = (h2){(_Float16)hnA_0, (_Float16)hnB_0};
            *(h2*)&hh[1][bh ^ 1][ja] = (h2){(_Float16)hnA_1, (_Float16)hnB_1};
        }

        // fused FC partial: VALU-only wave reduce, per batch
        float p0v = fmaf(hnA_0, wfcA, hnB_0 * wfcB);
        p0v += DPPF(p0v, 0x124);
        p0v += DPPF(p0v, 0x128);
        p0v = xor32_add(p0v);
        float p1v = fmaf(hnA_1, wfcA, hnB_1 * wfcB);
        p1v += DPPF(p1v, 0x124);
        p1v += DPPF(p1v, 0x128);
        p1v = xor32_add(p1v);
        pend_p0 = p0v; pend_id0 = id0;
        pend_p1 = p1v; pend_id1 = id1;

        lds_barrier();   // single barrier per step (h double-buffered)
    }

    // flush the final step's pipelined contributions
    if (fc_lane) {
        if ((unsigned)pend_id0 < (unsigned)P_)
            atomicAdd(&sums_lds[0][pend_id0 * O_ + kc], pend_p0);
        if ((unsigned)pend_id1 < (unsigned)P_)
            atomicAdd(&sums_lds[1][pend_id1 * O_ + kc], pend_p1);
    }
    if (tid == 0) {
        if ((unsigned)pend_id0 < (unsigned)P_)
            atomicAdd(&counts_lds[0][pend_id0], 1.f);
        if ((unsigned)pend_id1 < (unsigned)P_)
            atomicAdd(&counts_lds[1][pend_id1], 1.f);
    }
    __syncthreads();

    // ---- writeback (block owns slices b0, b1 exclusively) ----
    for (int i = tid; i < P_ * O_; i += 256) {
        sums[(size_t)b0 * P_ * O_ + i] = sums_lds[0][i];
        sums[(size_t)b1 * P_ * O_ + i] = sums_lds[1][i];
    }
    for (int i = tid; i < P_; i += 256) {
        counts[(size_t)b0 * P_ + i] = counts_lds[0][i];
        counts[(size_t)b1 * P_ + i] = counts_lds[1][i];
    }
}

// out[b,p,o] = (sums[b,p,o] + cnt*b_fc[o]) / max(cnt,1)
__global__ void finalize_kernel(const float* __restrict__ sums,
                                const float* __restrict__ counts,
                                const float* __restrict__ b_fc,
                                float* __restrict__ out)
{
    const int idx = blockIdx.x * blockDim.x + threadIdx.x;
    if (idx >= B_ * P_ * O_) return;
    const int o  = idx % O_;
    const int bp = idx / O_;
    const float cnt = counts[bp];
    const float denom = (cnt > 0.f) ? cnt : 1.f;
    out[idx] = (sums[idx] + cnt * b_fc[o]) / denom;
}

extern "C" void kernel_launch(void* const* d_in, const int* in_sizes, int n_in,
                              void* d_out, int out_size, void* d_ws, size_t ws_size,
                              hipStream_t stream) {
    const float* x    = (const float*)d_in[0];
    const float* W_ih = (const float*)d_in[1];
    const float* W_hh = (const float*)d_in[2];
    const float* b_ih = (const float*)d_in[3];
    const float* b_hh = (const float*)d_in[4];
    const float* W_fc = (const float*)d_in[5];
    const float* b_fc = (const float*)d_in[6];
    // d_in[7] = num_photos (==P_, fixed by the problem)

    float* out    = (float*)d_out;
    float* sums   = (float*)d_ws;                 // B*P*3 floats
    float* counts = sums + (size_t)B_ * P_ * O_;  // B*P floats
    // sums/counts fully overwritten by lstm_fused — no memset needed.

    lstm_fused<<<B_ / 2, 256, 0, stream>>>(x, W_ih, W_hh, b_ih, b_hh, W_fc,
                                           sums, counts);

    const int n = B_ * P_ * O_;
    finalize_kernel<<<(n + 255) / 256, 256, 0, stream>>>(sums, counts, b_fc, out);
}

// Round 6
// 8815.227 us; speedup vs baseline: 1.2004x; 1.2004x over previous
//
#include <hip/hip_runtime.h>

// Problem constants (fixed by reference setup)
#define B_ 32
#define T_ 8192
#define I_ 16
#define H_ 128
#define P_ 1024
#define O_ 3

typedef _Float16 h2 __attribute__((ext_vector_type(2)));
typedef _Float16 h4 __attribute__((ext_vector_type(4)));
typedef _Float16 h8 __attribute__((ext_vector_type(8)));

// R11: v_dot2_f32_f16 measured-slow (~6 cy/wave-instr; fits R7/R10 timing
// system exactly). Same MACs via v_fma_mix_f32 (f16 operands, fp32 accum,
// full-rate 2cy on the fp32 FMA pipe — m07: scalar fp32 FMA is full rate).
// 2 instrs per f16-pair instead of 1 dot2: 288x2=576 cy < 144x6=864 cy.
// Drop-in FDOT2 replacement; arithmetic semantics identical (f16 mult
// exact into fp32 FMA).
__device__ __forceinline__ float fmamix2(h2 a, h2 b, float c) {
    asm("v_fma_mix_f32 %0, %1, %2, %0 op_sel_hi:[1,1,0]"
        : "+v"(c) : "v"(a), "v"(b));
    asm("v_fma_mix_f32 %0, %1, %2, %0 op_sel:[1,1,0] op_sel_hi:[1,1,0]"
        : "+v"(c) : "v"(a), "v"(b));
    return c;
}
#define FDOT2(a, b, c) fmamix2((a), (b), (c))

// ---- macro machinery: (gate g 0..3, m 0..3, e 0..3) ------------------------
#define FORME(M, g) M(g,0,0) M(g,0,1) M(g,0,2) M(g,0,3) \
                    M(g,1,0) M(g,1,1) M(g,1,2) M(g,1,3) \
                    M(g,2,0) M(g,2,1) M(g,2,2) M(g,2,3) \
                    M(g,3,0) M(g,3,1) M(g,3,2) M(g,3,3)
#define FORALL(M) FORME(M,0) FORME(M,1) FORME(M,2) FORME(M,3)
#define FORG(M) M(0) M(1) M(2) M(3)

// DPP (quad_perm / row_ror): pure-VALU cross-lane, no LDS round-trip.
#define DPPF(v, ctrl) \
    __int_as_float(__builtin_amdgcn_mov_dpp(__float_as_int(v), (ctrl), 0xF, 0xF, true))

// xor32-add via gfx950 v_permlane32_swap_b32 (pure VALU).
__device__ __forceinline__ float xor32_add(float p) {
    float a = p, b = p;
    asm("v_permlane32_swap_b32 %0, %1" : "+v"(a), "+v"(b));
    return a + b;
}

__device__ __forceinline__ float tanh_f(float x) {
    return 2.f / (1.f + __expf(-2.f * x)) - 1.f;
}
__device__ __forceinline__ h4 cvt4(float4 v) {
    return (h4){(_Float16)v.x, (_Float16)v.y, (_Float16)v.z, (_Float16)v.w};
}

// LDS-only barrier: drain DS ops + s_barrier, without __syncthreads' vmcnt(0)
// drain (x-prefetch loads are consumed via register dependency).
__device__ __forceinline__ void lds_barrier() {
    asm volatile("s_waitcnt lgkmcnt(0)\n\ts_barrier" ::: "memory");
}

// Structure = R7/R8 (passed twice): 256 threads (4 waves, 1 wave/SIMD),
// 32 blocks (1 batch each — R10 proved wall-time favors max CU parallelism).
// Thread = (q, kc): q=0..63 owns unit pair (2q, 2q+1); kc=quad lane 0..3
// owns h-slice {kc*8+32m+e}. f16 weights in named h2 scalars, fp32 accum,
// c fp32, single lds_barrier per step, VALU-only FC reduce, atomics
// pipelined one step. Only change vs R8: FDOT2 -> fma_mix pair; junk-warm
// blocks removed (R8 measured null).
__global__ __launch_bounds__(256, 1) __attribute__((amdgpu_waves_per_eu(1, 1)))
void lstm_fused(
    const float* __restrict__ x,      // [B,T,16]
    const float* __restrict__ W_ih,   // [512,16]
    const float* __restrict__ W_hh,   // [512,128]
    const float* __restrict__ b_ih,   // [512]
    const float* __restrict__ b_hh,   // [512]
    const float* __restrict__ W_fc,   // [3,128]
    float* __restrict__ sums,         // [B,P,3]  (fully overwritten per block)
    float* __restrict__ counts)       // [B,P]    (fully overwritten per block)
{
    const int b   = blockIdx.x;
    const int tid = threadIdx.x;
    const int q   = tid >> 2;        // unit-pair index 0..63
    const int kc  = tid & 3;
    const int ja  = 2 * q;
    const int jb  = 2 * q + 1;

    __shared__ __align__(16) _Float16 hh[2][H_];       // hidden state, f16
    __shared__ __align__(16) _Float16 xt[2][16 * I_];  // x tile, f16
    __shared__ float sums_lds[P_ * O_];                // 12 KB
    __shared__ float counts_lds[P_];                   // 4 KB

    // ---- weights -> f16 half2 named scalars (128 + 16 = 144 VGPRs) ----
    const float* wrA0 = W_hh + (0 * H_ + ja) * H_;
    const float* wrA1 = W_hh + (1 * H_ + ja) * H_;
    const float* wrA2 = W_hh + (2 * H_ + ja) * H_;
    const float* wrA3 = W_hh + (3 * H_ + ja) * H_;
    const float* wrB0 = W_hh + (0 * H_ + jb) * H_;
    const float* wrB1 = W_hh + (1 * H_ + jb) * H_;
    const float* wrB2 = W_hh + (2 * H_ + jb) * H_;
    const float* wrB3 = W_hh + (3 * H_ + jb) * H_;
    // slot (g,m,e) holds W_hh[g*128+j][kc*8+32m+2e .. +1]
    #define WLOADA(g, m, e) h2 WA##g##_##m##_##e = (h2){ \
        (_Float16)wrA##g[kc * 8 + 32 * (m) + 2 * (e)], \
        (_Float16)wrA##g[kc * 8 + 32 * (m) + 2 * (e) + 1]};
    #define WLOADB(g, m, e) h2 WB##g##_##m##_##e = (h2){ \
        (_Float16)wrB##g[kc * 8 + 32 * (m) + 2 * (e)], \
        (_Float16)wrB##g[kc * 8 + 32 * (m) + 2 * (e) + 1]};
    FORALL(WLOADA)
    FORALL(WLOADB)

    // W_ih: gate g, x-chunk [kc*4, kc*4+4) as 2 half2, per unit
    #define ULOADA(g) \
        h2 UA##g##_0 = (h2){(_Float16)W_ih[((g) * H_ + ja) * I_ + kc * 4 + 0], \
                            (_Float16)W_ih[((g) * H_ + ja) * I_ + kc * 4 + 1]}; \
        h2 UA##g##_1 = (h2){(_Float16)W_ih[((g) * H_ + ja) * I_ + kc * 4 + 2], \
                            (_Float16)W_ih[((g) * H_ + ja) * I_ + kc * 4 + 3]};
    #define ULOADB(g) \
        h2 UB##g##_0 = (h2){(_Float16)W_ih[((g) * H_ + jb) * I_ + kc * 4 + 0], \
                            (_Float16)W_ih[((g) * H_ + jb) * I_ + kc * 4 + 1]}; \
        h2 UB##g##_1 = (h2){(_Float16)W_ih[((g) * H_ + jb) * I_ + kc * 4 + 2], \
                            (_Float16)W_ih[((g) * H_ + jb) * I_ + kc * 4 + 3]};
    FORG(ULOADA)
    FORG(ULOADB)

    // lane kc activates gate kc for both units
    const float biasA = b_ih[kc * H_ + ja] + b_hh[kc * H_ + ja];
    const float biasB = b_ih[kc * H_ + jb] + b_hh[kc * H_ + jb];
    const float wfcA  = (kc < 3) ? W_fc[kc * H_ + ja] : 0.f;
    const float wfcB  = (kc < 3) ? W_fc[kc * H_ + jb] : 0.f;

    // FC atomic lanes: reduce covers lane-xor {4,8,32} (row_ror x2 +
    // permlane32); remaining xor16 handled by 2-way same-address atomic from
    // lanes {kc, 16+kc}. Mask bits 2,3,5 of the lane id.
    const bool fc_lane = ((tid & 0x2C) == 0) && (kc < 3);

    // ---- init LDS ----
    for (int i = tid; i < P_ * O_; i += 256) sums_lds[i] = 0.f;
    for (int i = tid; i < P_;      i += 256) counts_lds[i] = 0.f;
    if (tid < H_) hh[0][tid] = (_Float16)0.f;

    const float* xb = x + (size_t)b * T_ * I_;
    float4 xr4 = make_float4(0.f, 0.f, 0.f, 0.f);
    if (tid < 64) {                       // tile 0 = steps 0..15
        xr4 = ((const float4*)xb)[tid];
        *(h4*)&xt[0][tid * 4] = cvt4(xr4);
    }
    float cA = 0.f, cB = 0.f;
    float pend_p = 0.f;   // pipelined FC partial (from step t-1)
    int   pend_id = 0;
    __syncthreads();

    #pragma unroll 1
    for (int t = 0; t < T_; ++t) {
        const int off = t & 15;
        const int btx = (t >> 4) & 1;
        const int bh  = t & 1;

        // ---- pipelined FC/count atomics from step t-1 (off the critical
        // path: complete during the dot phase, long done by the barrier).
        if (t != 0) {
            if (fc_lane && (unsigned)pend_id < (unsigned)P_)
                atomicAdd(&sums_lds[pend_id * O_ + kc], pend_p);
            if (tid == 0 && (unsigned)pend_id < (unsigned)P_)
                atomicAdd(&counts_lds[pend_id], 1.f);
        }

        // x prefetch (wave 0): issue tile t+16 at off==0, commit at off==8
        if (tid < 64) {
            if (off == 0 && t + 16 < T_)
                xr4 = ((const float4*)(xb + (t + 16) * I_))[tid];
            if (off == 8 && t + 8 < T_)
                *(h4*)&xt[btx ^ 1][tid * 4] = cvt4(xr4);
        }

        const h4 xv4 = *(const h4*)&xt[btx][off * I_ + kc * 4];
        const h2 xv0 = __builtin_shufflevector(xv4, xv4, 0, 1);
        const h2 xv1 = __builtin_shufflevector(xv4, xv4, 2, 3);
        const int id = (int)(float)xt[btx][off * I_ + 2];   // exact (id<2048)

        // 8 gate-row partials (4 gates x 2 units) over the kc h-slice.
        // Both units consume the SAME h8 loads: h-read burst stays 4x b128.
        float aA0 = 0.f, aA1 = 0.f, aA2 = 0.f, aA3 = 0.f;
        float aB0 = 0.f, aB1 = 0.f, aB2 = 0.f, aB3 = 0.f;
        #define HD(m) { \
            h8 hv = *(const h8*)&hh[bh][kc * 8 + 32 * (m)]; \
            h2 p0 = __builtin_shufflevector(hv, hv, 0, 1); \
            h2 p1 = __builtin_shufflevector(hv, hv, 2, 3); \
            h2 p2 = __builtin_shufflevector(hv, hv, 4, 5); \
            h2 p3 = __builtin_shufflevector(hv, hv, 6, 7); \
            aA0 = FDOT2(p0, WA0_##m##_0, aA0); aA0 = FDOT2(p1, WA0_##m##_1, aA0); \
            aA0 = FDOT2(p2, WA0_##m##_2, aA0); aA0 = FDOT2(p3, WA0_##m##_3, aA0); \
            aA1 = FDOT2(p0, WA1_##m##_0, aA1); aA1 = FDOT2(p1, WA1_##m##_1, aA1); \
            aA1 = FDOT2(p2, WA1_##m##_2, aA1); aA1 = FDOT2(p3, WA1_##m##_3, aA1); \
            aA2 = FDOT2(p0, WA2_##m##_0, aA2); aA2 = FDOT2(p1, WA2_##m##_1, aA2); \
            aA2 = FDOT2(p2, WA2_##m##_2, aA2); aA2 = FDOT2(p3, WA2_##m##_3, aA2); \
            aA3 = FDOT2(p0, WA3_##m##_0, aA3); aA3 = FDOT2(p1, WA3_##m##_1, aA3); \
            aA3 = FDOT2(p2, WA3_##m##_2, aA3); aA3 = FDOT2(p3, WA3_##m##_3, aA3); \
            aB0 = FDOT2(p0, WB0_##m##_0, aB0); aB0 = FDOT2(p1, WB0_##m##_1, aB0); \
            aB0 = FDOT2(p2, WB0_##m##_2, aB0); aB0 = FDOT2(p3, WB0_##m##_3, aB0); \
            aB1 = FDOT2(p0, WB1_##m##_0, aB1); aB1 = FDOT2(p1, WB1_##m##_1, aB1); \
            aB1 = FDOT2(p2, WB1_##m##_2, aB1); aB1 = FDOT2(p3, WB1_##m##_3, aB1); \
            aB2 = FDOT2(p0, WB2_##m##_0, aB2); aB2 = FDOT2(p1, WB2_##m##_1, aB2); \
            aB2 = FDOT2(p2, WB2_##m##_2, aB2); aB2 = FDOT2(p3, WB2_##m##_3, aB2); \
            aB3 = FDOT2(p0, WB3_##m##_0, aB3); aB3 = FDOT2(p1, WB3_##m##_1, aB3); \
            aB3 = FDOT2(p2, WB3_##m##_2, aB3); aB3 = FDOT2(p3, WB3_##m##_3, aB3); }
        HD(0) HD(1) HD(2) HD(3)
        // x contribution
        aA0 = FDOT2(xv0, UA0_0, aA0); aA0 = FDOT2(xv1, UA0_1, aA0);
        aA1 = FDOT2(xv0, UA1_0, aA1); aA1 = FDOT2(xv1, UA1_1, aA1);
        aA2 = FDOT2(xv0, UA2_0, aA2); aA2 = FDOT2(xv1, UA2_1, aA2);
        aA3 = FDOT2(xv0, UA3_0, aA3); aA3 = FDOT2(xv1, UA3_1, aA3);
        aB0 = FDOT2(xv0, UB0_0, aB0); aB0 = FDOT2(xv1, UB0_1, aB0);
        aB1 = FDOT2(xv0, UB1_0, aB1); aB1 = FDOT2(xv1, UB1_1, aB1);
        aB2 = FDOT2(xv0, UB2_0, aB2); aB2 = FDOT2(xv1, UB2_1, aB2);
        aB3 = FDOT2(xv0, UB3_0, aB3); aB3 = FDOT2(xv1, UB3_1, aB3);

        // quad butterfly (xor1=0xB1, xor2=0x4E): all 4 lanes get all 8 totals
        float s_;
        s_ = DPPF(aA0, 0xB1); aA0 += s_;
        s_ = DPPF(aA1, 0xB1); aA1 += s_;
        s_ = DPPF(aA2, 0xB1); aA2 += s_;
        s_ = DPPF(aA3, 0xB1); aA3 += s_;
        s_ = DPPF(aB0, 0xB1); aB0 += s_;
        s_ = DPPF(aB1, 0xB1); aB1 += s_;
        s_ = DPPF(aB2, 0xB1); aB2 += s_;
        s_ = DPPF(aB3, 0xB1); aB3 += s_;
        s_ = DPPF(aA0, 0x4E); aA0 += s_;
        s_ = DPPF(aA1, 0x4E); aA1 += s_;
        s_ = DPPF(aA2, 0x4E); aA2 += s_;
        s_ = DPPF(aA3, 0x4E); aA3 += s_;
        s_ = DPPF(aB0, 0x4E); aB0 += s_;
        s_ = DPPF(aB1, 0x4E); aB1 += s_;
        s_ = DPPF(aB2, 0x4E); aB2 += s_;
        s_ = DPPF(aB3, 0x4E); aB3 += s_;

        // lane kc activates gate kc for both units (i,f,o sigmoid; g tanh)
        float tgA = (kc == 0) ? aA0 : (kc == 1) ? aA1 : (kc == 2) ? aA2 : aA3;
        float tgB = (kc == 0) ? aB0 : (kc == 1) ? aB1 : (kc == 2) ? aB2 : aB3;
        tgA += biasA;
        tgB += biasB;
        const bool  isg  = (kc == 2);
        const float argA = isg ? (tgA + tgA) : tgA;
        const float argB = isg ? (tgB + tgB) : tgB;
        const float sfA  = 1.f / (1.f + __expf(-argA));
        const float sfB  = 1.f / (1.f + __expf(-argB));
        const float actA = isg ? (sfA + sfA - 1.f) : sfA;   // tanh = 2*sig(2x)-1
        const float actB = isg ? (sfB + sfB - 1.f) : sfB;

        // gather each unit's 4 activated gates (quad_perm broadcasts)
        const float giA = DPPF(actA, 0x00);
        const float gfA = DPPF(actA, 0x55);
        const float ggA = DPPF(actA, 0xAA);
        const float goA = DPPF(actA, 0xFF);
        const float giB = DPPF(actB, 0x00);
        const float gfB = DPPF(actB, 0x55);
        const float ggB = DPPF(actB, 0xAA);
        const float goB = DPPF(actB, 0xFF);
        cA = fmaf(gfA, cA, giA * ggA);
        cB = fmaf(gfB, cB, giB * ggB);
        const float hnA = goA * tanh_f(cA);
        const float hnB = goB * tanh_f(cB);

        if (kc == 0) {      // publish h_t: contiguous f16 pair, one b32 write
            h2 hp = (h2){(_Float16)hnA, (_Float16)hnB};
            *(h2*)&hh[bh ^ 1][ja] = hp;
        }

        // fused FC partial: VALU-only wave reduce (row_ror:4 + row_ror:8 +
        // permlane32_swap); xor16 left for the 2-way same-address atomic.
        float p = fmaf(hnA, wfcA, hnB * wfcB);
        p += DPPF(p, 0x124);
        p += DPPF(p, 0x128);
        p = xor32_add(p);
        pend_p  = p;
        pend_id = id;

        lds_barrier();   // single barrier per step (h double-buffered)
    }

    // flush the final step's pipelined contribution
    if (fc_lane && (unsigned)pend_id < (unsigned)P_)
        atomicAdd(&sums_lds[pend_id * O_ + kc], pend_p);
    if (tid == 0 && (unsigned)pend_id < (unsigned)P_)
        atomicAdd(&counts_lds[pend_id], 1.f);
    __syncthreads();

    // ---- writeback (block b owns slice b exclusively) ----
    float* sums_g = sums + (size_t)b * P_ * O_;
    for (int i = tid; i < P_ * O_; i += 256) sums_g[i] = sums_lds[i];
    float* cnt_g = counts + (size_t)b * P_;
    for (int i = tid; i < P_; i += 256) cnt_g[i] = counts_lds[i];
}

// out[b,p,o] = (sums[b,p,o] + cnt*b_fc[o]) / max(cnt,1)
__global__ void finalize_kernel(const float* __restrict__ sums,
                                const float* __restrict__ counts,
                                const float* __restrict__ b_fc,
                                float* __restrict__ out)
{
    const int idx = blockIdx.x * blockDim.x + threadIdx.x;
    if (idx >= B_ * P_ * O_) return;
    const int o  = idx % O_;
    const int bp = idx / O_;
    const float cnt = counts[bp];
    const float denom = (cnt > 0.f) ? cnt : 1.f;
    out[idx] = (sums[idx] + cnt * b_fc[o]) / denom;
}

extern "C" void kernel_launch(void* const* d_in, const int* in_sizes, int n_in,
                              void* d_out, int out_size, void* d_ws, size_t ws_size,
                              hipStream_t stream) {
    const float* x    = (const float*)d_in[0];
    const float* W_ih = (const float*)d_in[1];
    const float* W_hh = (const float*)d_in[2];
    const float* b_ih = (const float*)d_in[3];
    const float* b_hh = (const float*)d_in[4];
    const float* W_fc = (const float*)d_in[5];
    const float* b_fc = (const float*)d_in[6];
    // d_in[7] = num_photos (==P_, fixed by the problem)

    float* out    = (float*)d_out;
    float* sums   = (float*)d_ws;                 // B*P*3 floats
    float* counts = sums + (size_t)B_ * P_ * O_;  // B*P floats
    // sums/counts fully overwritten by lstm_fused — no memset needed.

    lstm_fused<<<B_, 256, 0, stream>>>(x, W_ih, W_hh, b_ih, b_hh, W_fc,
                                       sums, counts);

    const int n = B_ * P_ * O_;
    finalize_kernel<<<(n + 255) / 256, 256, 0, stream>>>(sums, counts, b_fc, out);
}